// Round 6
// baseline (71.082 us; speedup 1.0000x reference)
//
#include <hip/hip_runtime.h>

#define SIDE 128
#define PI_F 3.14159265358979f
// Window half-width bound: kept terms satisfy c*d2 < ln(coef)+32 with
// coef <= 2*4pi/0.5 = 50.27, c = pi*4pi/ff_b >= 2*pi^2 = 19.74 => r <= 1.35.
// A 3-col window centered at round(cx) covers |j-cx| <= 1.5 > 1.35 at any
// sub-pixel alignment, so no per-blob window math is needed at all.
#define RMAX 1.4f
#define BLK 1024

// One block per (batch, 2-row stripe): grid (64,4) = 256 blocks x 1024 thr.
// Phase 1: both coord rounds prefetched up-front (one latency exposure),
// ballot-compacted into LDS (1 same-address atomic per wave per round).
// Phase 2: branch-free fixed 2x3 window per (atom,f): 5 exps + 6 ds_add.
// Phase 3: coalesced float4 store of the disjoint stripe (overwrites poison;
// no zero kernel, no global atomics).
__global__ void __launch_bounds__(BLK) potential_stripe(
        const float* __restrict__ coords,
        const float* __restrict__ ff_a,
        const float* __restrict__ ff_b,
        float* __restrict__ out,
        int A) {
    const int s    = blockIdx.x;        // stripe index, rows [2s, 2s+1]
    const int b    = blockIdx.y;
    const int row0 = s * 2;
    const int t    = threadIdx.x;       // 0..1023
    const int lane = t & 63;

    __shared__ float img[2 * SIDE];     // 1 KB stripe accumulator
    __shared__ int   cnt;
    __shared__ float lx[2048], ly[2048];
    __shared__ int   li[2048];

    if (t < 2 * SIDE) img[t] = 0.0f;
    if (t == 0) cnt = 0;

    const float* cb = coords + (size_t)b * A * 3;

    // ---- Phase 1a: prefetch both rounds' coords (independent loads, all
    // in flight before any use) ----
    int aA = t, aB = t + BLK;           // A=2048 = 2*BLK exactly
    float xA = 0.f, yA = 0.f, xB = 0.f, yB = 0.f;
    if (aA < A) { xA = cb[aA * 3 + 0]; yA = cb[aA * 3 + 1]; }
    if (aB < A) { xB = cb[aB * 3 + 0]; yB = cb[aB * 3 + 1]; }

    __syncthreads();                    // img/cnt init visible

    // ---- Phase 1b: two ballot-compaction rounds ----
    const float ylo = (float)row0 - RMAX;
    const float yhi = (float)(row0 + 1) + RMAX;
    #pragma unroll
    for (int rnd = 0; rnd < 2; ++rnd) {
        int   a  = rnd ? aB : aA;
        float cx = (rnd ? xB : xA) + 64.0f;
        float cy = (rnd ? yB : yA) + 64.0f;
        bool keep = (a < A) & (cy >= ylo) & (cy <= yhi) &
                    (cx >= -RMAX) & (cx <= 127.0f + RMAX);
        unsigned long long m = __ballot(keep);
        int nw  = __popcll(m);
        int pos = __popcll(m & ((1ull << lane) - 1ull));
        int base = 0;
        if (lane == 0 && nw) base = atomicAdd(&cnt, nw);
        base = __shfl(base, 0);
        if (keep) {
            int k = base + pos;
            lx[k] = cx; ly[k] = cy; li[k] = a;
        }
    }
    __syncthreads();

    // ---- Phase 2: branch-free 2x3 scatter per (atom,f) ----
    const int n = cnt;                  // busiest stripe ~400
    for (int k = t; k < n; k += BLK) {
        float cx = lx[k];
        float cy = ly[k];
        int   a  = li[k];
        int   jc = (int)floorf(cx + 0.5f);     // nearest column
        float d0 = (float)(jc - 1) - cx;
        float d1 = d0 + 1.0f;
        float d2 = d0 + 2.0f;
        float dy0 = (float)row0 - cy;
        float dy1 = dy0 + 1.0f;
        bool  ok0 = (jc - 1 >= 0) & (jc - 1 < SIDE);
        bool  ok1 = (jc     >= 0) & (jc     < SIDE);
        bool  ok2 = (jc + 1 >= 0) & (jc + 1 < SIDE);
        float* r0 = img;
        float* r1 = img + SIDE;
        #pragma unroll
        for (int f = 0; f < 5; ++f) {
            float fa = ff_a[a * 5 + f];
            float fb = ff_b[a * 5 + f];
            float invb = (4.0f * PI_F) / fb;
            float coef = fa * invb;
            float c    = -PI_F * invb;  // negative exponent scale
            // 5 exps: 2 row weights (coef folded in), 3 col weights.
            // Beyond the blob these underflow to 0 -> harmless adds.
            float wy0 = coef * __expf(c * dy0 * dy0);
            float wy1 = coef * __expf(c * dy1 * dy1);
            float w0  = __expf(c * d0 * d0);
            float w1  = __expf(c * d1 * d1);
            float w2  = __expf(c * d2 * d2);
            if (ok0) { atomicAdd(&r0[jc - 1], wy0 * w0);
                       atomicAdd(&r1[jc - 1], wy1 * w0); }
            if (ok1) { atomicAdd(&r0[jc    ], wy0 * w1);
                       atomicAdd(&r1[jc    ], wy1 * w1); }
            if (ok2) { atomicAdd(&r0[jc + 1], wy0 * w2);
                       atomicAdd(&r1[jc + 1], wy1 * w2); }
        }
    }
    __syncthreads();

    // ---- Phase 3: store the disjoint stripe (overwrites 0xAA poison) ----
    if (t < (2 * SIDE) / 4) {           // 64 float4 = 256 floats
        float4* ov = (float4*)(out + ((size_t)b * SIDE + row0) * SIDE);
        ov[t] = ((const float4*)img)[t];
    }
}

extern "C" void kernel_launch(void* const* d_in, const int* in_sizes, int n_in,
                              void* d_out, int out_size, void* d_ws, size_t ws_size,
                              hipStream_t stream) {
    const float* coords = (const float*)d_in[0];
    const float* ffa    = (const float*)d_in[1];
    const float* ffb    = (const float*)d_in[2];
    float* out = (float*)d_out;

    int A = in_sizes[1] / 5;            // 2048
    int B = in_sizes[0] / (A * 3);      // 4

    dim3 grid(SIDE / 2, B);             // (64 stripes, 4 batches) = 256 blocks
    potential_stripe<<<grid, BLK, 0, stream>>>(coords, ffa, ffb, out, A);
}

// Round 7
// 70.568 us; speedup vs baseline: 1.0073x; 1.0073x over previous
//
#include <hip/hip_runtime.h>

#define SIDE 128
#define PI_F 3.14159265358979f
// Window half-width bound: kept terms satisfy c*d2 < ln(coef)+32 with
// coef <= 2*4pi/0.5 = 50.27, c = pi*4pi/ff_b >= 2*pi^2 = 19.74 => r <= 1.35.
// A 3-col window centered at round(cx) covers |j-cx| <= 1.5 > 1.35 at any
// sub-pixel alignment => no per-blob window math needed.
#define RMAX 1.4f
#define BLK 512

// One block per (batch, 2-row stripe): grid (64,4) = 256 blocks x 512 thr.
// R7 = R5 (BLK=512, best measured) + R6's up-front prefetch (all 4 coord
// rounds in flight before any ballot) + R6's branch-free 2x3 inner window.
// Phase 1: ballot-compacted atom filter (1 same-address LDS atomic per wave
// per round). Phase 2: 5 exps + <=6 ds_add per (atom,f), no log/sqrt/window
// branching. Phase 3: coalesced float4 store of the disjoint stripe
// (overwrites 0xAA poison; no zero kernel, no global atomics).
__global__ void __launch_bounds__(BLK) potential_stripe(
        const float* __restrict__ coords,
        const float* __restrict__ ff_a,
        const float* __restrict__ ff_b,
        float* __restrict__ out,
        int A) {
    const int s    = blockIdx.x;        // stripe index, rows [2s, 2s+1]
    const int b    = blockIdx.y;
    const int row0 = s * 2;
    const int t    = threadIdx.x;       // 0..511
    const int lane = t & 63;

    __shared__ float img[2 * SIDE];     // 1 KB stripe accumulator
    __shared__ int   cnt;
    __shared__ float lx[2048], ly[2048];
    __shared__ int   li[2048];

    const float* cb = coords + (size_t)b * A * 3;

    // ---- Phase 1a: prefetch ALL 4 rounds' coords (8 independent loads in
    // flight before any use -> one latency exposure) ----
    float px[4], py[4];
    #pragma unroll
    for (int r = 0; r < 4; ++r) {       // A = 2048 = 4*BLK
        int a = t + r * BLK;
        px[r] = 0.f; py[r] = 0.f;
        if (a < A) { px[r] = cb[a * 3 + 0]; py[r] = cb[a * 3 + 1]; }
    }

    if (t < 2 * SIDE) img[t] = 0.0f;
    if (t == 0) cnt = 0;
    __syncthreads();

    // ---- Phase 1b: four ballot-compaction rounds (no loads inside) ----
    const float ylo = (float)row0 - RMAX;
    const float yhi = (float)(row0 + 1) + RMAX;
    #pragma unroll
    for (int r = 0; r < 4; ++r) {
        int   a  = t + r * BLK;
        float cx = px[r] + 64.0f;
        float cy = py[r] + 64.0f;
        bool keep = (a < A) & (cy >= ylo) & (cy <= yhi) &
                    (cx >= -RMAX) & (cx <= 127.0f + RMAX);
        unsigned long long m = __ballot(keep);
        int nw  = __popcll(m);
        int pos = __popcll(m & ((1ull << lane) - 1ull));
        int base = 0;
        if (lane == 0 && nw) base = atomicAdd(&cnt, nw);
        base = __shfl(base, 0);
        if (keep) {
            int k = base + pos;
            lx[k] = cx; ly[k] = cy; li[k] = a * 5;
        }
    }
    __syncthreads();

    // ---- Phase 2: branch-free 2x3 scatter per (atom,f) ----
    const int n = cnt;                  // busiest stripe ~400
    for (int k = t; k < n; k += BLK) {
        float cx = lx[k];
        float cy = ly[k];
        int   a5 = li[k];
        int   jc = (int)floorf(cx + 0.5f);     // nearest column
        float d0 = (float)(jc - 1) - cx;
        float d1 = d0 + 1.0f;
        float d2 = d0 + 2.0f;
        float dy0 = (float)row0 - cy;
        float dy1 = dy0 + 1.0f;
        bool  ok0 = (jc - 1 >= 0) & (jc - 1 < SIDE);
        bool  ok1 = (jc     >= 0) & (jc     < SIDE);
        bool  ok2 = (jc + 1 >= 0) & (jc + 1 < SIDE);
        float* r0 = img;
        float* r1 = img + SIDE;
        #pragma unroll
        for (int f = 0; f < 5; ++f) {
            float fa = ff_a[a5 + f];
            float fb = ff_b[a5 + f];
            float invb = (4.0f * PI_F) / fb;
            float coef = fa * invb;
            float c    = -PI_F * invb;  // negative exponent scale
            // 5 exps: 2 row weights (coef folded in), 3 col weights.
            // Outside the blob they underflow to 0 -> harmless adds.
            float wy0 = coef * __expf(c * dy0 * dy0);
            float wy1 = coef * __expf(c * dy1 * dy1);
            float w0  = __expf(c * d0 * d0);
            float w1  = __expf(c * d1 * d1);
            float w2  = __expf(c * d2 * d2);
            if (ok0) { atomicAdd(&r0[jc - 1], wy0 * w0);
                       atomicAdd(&r1[jc - 1], wy1 * w0); }
            if (ok1) { atomicAdd(&r0[jc    ], wy0 * w1);
                       atomicAdd(&r1[jc    ], wy1 * w1); }
            if (ok2) { atomicAdd(&r0[jc + 1], wy0 * w2);
                       atomicAdd(&r1[jc + 1], wy1 * w2); }
        }
    }
    __syncthreads();

    // ---- Phase 3: store the disjoint stripe (overwrites 0xAA poison) ----
    if (t < (2 * SIDE) / 4) {           // 64 float4 = 256 floats
        float4* ov = (float4*)(out + ((size_t)b * SIDE + row0) * SIDE);
        ov[t] = ((const float4*)img)[t];
    }
}

extern "C" void kernel_launch(void* const* d_in, const int* in_sizes, int n_in,
                              void* d_out, int out_size, void* d_ws, size_t ws_size,
                              hipStream_t stream) {
    const float* coords = (const float*)d_in[0];
    const float* ffa    = (const float*)d_in[1];
    const float* ffb    = (const float*)d_in[2];
    float* out = (float*)d_out;

    int A = in_sizes[1] / 5;            // 2048
    int B = in_sizes[0] / (A * 3);      // 4

    dim3 grid(SIDE / 2, B);             // (64 stripes, 4 batches) = 256 blocks
    potential_stripe<<<grid, BLK, 0, stream>>>(coords, ffa, ffb, out, A);
}

// Round 8
// 64.368 us; speedup vs baseline: 1.1043x; 1.0963x over previous
//
#include <hip/hip_runtime.h>

#define SIDE 128
#define PI_F 3.14159265358979f
// Max window half-width: r = sqrt((ln(coef)+32)/c), coef<=2*4pi/0.5=50.27,
// c = pi*4pi/ff_b >= 2*pi^2 = 19.74  =>  r <= 1.35. Use 1.4 for safety.
#define RMAX 1.4f
#define BLK 512

// R8 = exact revert to R5, the best-measured variant (63.9 us vs 70.6/71.1
// for the branch-free-inner variants R6/R7 — A/B isolated the fixed 2x3
// inner as the regression; exact per-blob windows are cheaper in practice).
//
// One block per (batch, 2-row stripe): grid (64,4) = 256 blocks, 512 thr.
// Phase 1: ballot-compacted atom filter (1 same-address LDS atomic per wave
// per round) storing cx,cy,idx in LDS. Phase 2: full-lane scatter of <=3x3
// separable Gaussian windows into a 2x128 LDS stripe via ds_add. Phase 3:
// coalesced float4 store of the disjoint stripe (overwrites 0xAA poison; no
// zero kernel, no global atomics).
__global__ void __launch_bounds__(BLK) potential_stripe(
        const float* __restrict__ coords,
        const float* __restrict__ ff_a,
        const float* __restrict__ ff_b,
        float* __restrict__ out,
        int A) {
    const int s    = blockIdx.x;        // stripe index, rows [2s, 2s+1]
    const int b    = blockIdx.y;
    const int row0 = s * 2;
    const int t    = threadIdx.x;       // 0..511
    const int lane = t & 63;

    __shared__ float img[2 * SIDE];     // 1 KB stripe accumulator
    __shared__ int   cnt;
    __shared__ float lx[2048], ly[2048];
    __shared__ int   li[2048];

    if (t < 2 * SIDE) img[t] = 0.0f;
    if (t == 0) cnt = 0;
    __syncthreads();

    const float* cb = coords + (size_t)b * A * 3;

    // ---- Phase 1: filter atoms by row window (all 5 f share the center) ----
    const float ylo = (float)row0 - RMAX;
    const float yhi = (float)(row0 + 1) + RMAX;
    for (int a0 = 0; a0 < A; a0 += BLK) {        // 4 rounds
        int a = a0 + t;
        float cx = 0.f, cy = 0.f;
        bool keep = false;
        if (a < A) {
            cx = cb[a * 3 + 0] + 64.0f;
            cy = cb[a * 3 + 1] + 64.0f;
            keep = (cy >= ylo) & (cy <= yhi) &
                   (cx >= -RMAX) & (cx <= 127.0f + RMAX);
        }
        unsigned long long m = __ballot(keep);
        int nw  = __popcll(m);
        int pos = __popcll(m & ((1ull << lane) - 1ull));
        int base = 0;
        if (lane == 0 && nw) base = atomicAdd(&cnt, nw);
        base = __shfl(base, 0);
        if (keep) {
            int k = base + pos;
            lx[k] = cx; ly[k] = cy; li[k] = a;
        }
    }
    __syncthreads();

    // ---- Phase 2: scatter surviving blobs into the LDS stripe ----
    const int n = cnt;                  // busiest stripe ~400
    for (int k = t; k < n; k += BLK) {
        float cx = lx[k];
        float cy = ly[k];
        int   a  = li[k];
        #pragma unroll
        for (int f = 0; f < 5; ++f) {
            float fa = ff_a[a * 5 + f];
            float fb = ff_b[a * 5 + f];
            float invb = (4.0f * PI_F) / fb;
            float coef = fa * invb;     // peak amplitude
            float c    = PI_F * invb;   // exponent scale
            // keep terms > ~1e-14 abs (pass threshold is 3.48)
            float r = sqrtf((__logf(coef) + 32.0f) / c);

            int i0 = max(row0,     (int)ceilf(cy - r));
            int i1 = min(row0 + 1, (int)floorf(cy + r));
            int j0 = max(0,        (int)ceilf(cx - r));
            int j1 = min(SIDE - 1, (int)floorf(cx + r));

            for (int i = i0; i <= i1; ++i) {        // <= 2 rows
                float dy  = (float)i - cy;
                float wyi = coef * __expf(-c * dy * dy);
                float* rowp = img + (i - row0) * SIDE;
                for (int j = j0; j <= j1; ++j) {    // <= 3 cols
                    float dx = (float)j - cx;
                    atomicAdd(&rowp[j], wyi * __expf(-c * dx * dx)); // ds_add
                }
            }
        }
    }
    __syncthreads();

    // ---- Phase 3: store the disjoint stripe (overwrites 0xAA poison) ----
    if (t < (2 * SIDE) / 4) {           // 64 float4 = 256 floats
        float4* ov = (float4*)(out + ((size_t)b * SIDE + row0) * SIDE);
        ov[t] = ((const float4*)img)[t];
    }
}

extern "C" void kernel_launch(void* const* d_in, const int* in_sizes, int n_in,
                              void* d_out, int out_size, void* d_ws, size_t ws_size,
                              hipStream_t stream) {
    const float* coords = (const float*)d_in[0];
    const float* ffa    = (const float*)d_in[1];
    const float* ffb    = (const float*)d_in[2];
    float* out = (float*)d_out;

    int A = in_sizes[1] / 5;            // 2048
    int B = in_sizes[0] / (A * 3);      // 4

    dim3 grid(SIDE / 2, B);             // (64 stripes, 4 batches) = 256 blocks
    potential_stripe<<<grid, BLK, 0, stream>>>(coords, ffa, ffb, out, A);
}